// Round 6
// baseline (223.627 us; speedup 1.0000x reference)
//
#include <hip/hip_runtime.h>
#include <hip/hip_bf16.h>
#include <math.h>

// ---------------- ws layout (float/u32 offsets) ----------------
#define BQ0 320
#define BQ1 4480
#define BQ2 8640
#define BQ3 12800
#define BQ4 12928
#define GT0 12932
#define GT1 13444
#define GT2 15492
// Packed f16 MFMA weight fragments, x64-scaled, single RNE f16.
// fi 0..23 = layers 1..3 ((l*2+s)*4+ft), fi 24..27 = layer 0 (K rows 5..31 zero).
// K-order of layers 1..3 frags and of W4P is PERMUTED so that the previous
// layer's accumulator registers (after gelu+pkrtz) directly form the next
// layer's B-fragment: B-slot t holds prev physical row
//   r(t) = 32*(t>>5) + 16*((t>>2)&1) + 4*((t>>3)&3) + (t&3).
#define FRAG_OFF 23684
#define W4P 38020
#define WSCALE 64.0f
#define WINV   0.015625f

// HARD RULE (r3-r5 lessons): NO inline-asm VALU anywhere in this kernel.
// gfx950 has no packed f32 min/max (r3); asm reading MFMA results races
// (r4); asm reading v_rcp/v_exp results also races — the hazard recognizer
// does not pad trans-forwarding delays for INLINEASM consumers (r5).
// Everything below is compiler-visible builtins only.

typedef _Float16 f16x8 __attribute__((ext_vector_type(8)));
typedef _Float16 f16x2 __attribute__((ext_vector_type(2)));
typedef float floatx4 __attribute__((ext_vector_type(4)));
typedef float floatx2 __attribute__((ext_vector_type(2)));
typedef unsigned int uintx4 __attribute__((ext_vector_type(4)));

__device__ inline floatx4 mfma16(f16x8 a, f16x8 b, floatx4 c) {
    return __builtin_amdgcn_mfma_f32_16x16x32_f16(a, b, c, 0, 0, 0);
}
__device__ inline floatx2 splat2(float c) { return (floatx2){c, c}; }

// single-inst packed f32->f16 pair conversion (RTZ); returns __fp16x2.
__device__ inline unsigned int pkrtz(float a, float b) {
    auto r = __builtin_amdgcn_cvt_pkrtz(a, b);
    return __builtin_bit_cast(unsigned int, r);
}
// exact RNE pack (prep-side / layer-0 staging)
__device__ inline unsigned int pack_f16(float a, float b) {
    unsigned short ua = __builtin_bit_cast(unsigned short, (_Float16)a);
    unsigned short ub = __builtin_bit_cast(unsigned short, (_Float16)b);
    return (unsigned int)ua | ((unsigned int)ub << 16);
}
__device__ inline f16x8 frag_from(uint2 a, uint2 b) {
    uintx4 u = {a.x, a.y, b.x, b.y};
    return __builtin_bit_cast(f16x8, u);
}
__device__ inline f16x2 h2(unsigned int u) { return __builtin_bit_cast(f16x2, u); }

#if __has_builtin(__builtin_amdgcn_fdot2)
__device__ inline float fdot2f(f16x2 a, f16x2 b, float c) {
    return __builtin_amdgcn_fdot2(a, b, c, false);
}
#else
__device__ inline float fdot2f(f16x2 a, f16x2 b, float c) {
    return fmaf((float)a[0], (float)b[0], fmaf((float)a[1], (float)b[1], c));
}
#endif

// Packed-pair gelu: 0.5*(x + |x|*erf_mag(|x|/sqrt2)), AS 7.1.25 erf.
// TRANS-DIET version (r2 counters: 4 quarter-rate trans/pair = ~55% of kernel
// issue time). v_rcp replaced by NR reciprocal: z clamped to [0,3] (erfc(3)
// = 2.2e-5, tail error <= x*1.1e-5), so den = 1+0.47047*z in [1, 2.4114];
// minimax linear seed (rel err 0.0936) + 2 Newton iters -> rel err 7.7e-5.
// Sign trick: iterate r -> -1/d (r = r*(d*r+2) keeps the NR form with no
// negates) and fold t = -r into the A&S polynomial, so er = 1 + (r*q)*e.
// Remaining trans: 2x exp2 per pair. Added error vs baseline <= ~5e-5.
__device__ inline floatx2 gelu2(floatx2 x) {
    floatx2 ax = __builtin_elementwise_abs(x);
    floatx2 z  = ax * splat2(0.70710678118654752f);
    floatx2 zc = __builtin_elementwise_min(z, splat2(3.0f));
    floatx2 d  = __builtin_elementwise_fma(zc, splat2(0.47047f), splat2(1.0f));
    // r ~ -1/d
    floatx2 r  = __builtin_elementwise_fma(d, splat2(0.375880f), splat2(-1.282272f));
    floatx2 g  = __builtin_elementwise_fma(d, r, splat2(2.0f));
    r = r * g;
    g = __builtin_elementwise_fma(d, r, splat2(2.0f));
    r = r * g;
    // q(t)=0.7478556 t^2 - 0.0958798 t + 0.3480242 with t=-r; p = t*q = -(r*q)
    floatx2 q  = __builtin_elementwise_fma(r, splat2(0.7478556f), splat2(0.0958798f));
    q = __builtin_elementwise_fma(r, q, splat2(0.3480242f));
    floatx2 rq = r * q;
    floatx2 zz = zc * zc;
    floatx2 ea = zz * splat2(-1.44269504088896f);
    floatx2 e;
    e.x = __builtin_amdgcn_exp2f(ea.x);
    e.y = __builtin_amdgcn_exp2f(ea.y);
    floatx2 er = __builtin_elementwise_fma(rq, e, splat2(1.0f));  // erf(z)
    return __builtin_elementwise_fma(ax, er, x) * splat2(0.5f);
}

__device__ inline float tanh_fast(float x) {
    float e = __builtin_amdgcn_exp2f(x * 2.88539008177793f);
    return fmaf(-2.0f, __builtin_amdgcn_rcpf(e + 1.0f), 1.0f);
}

__device__ void block_minmax(float mn, float mx, float* omn, float* omx,
                             float* smn, float* smx) {
    __syncthreads();
    #pragma unroll
    for (int off = 32; off > 0; off >>= 1) {
        mn = fminf(mn, __shfl_down(mn, off));
        mx = fmaxf(mx, __shfl_down(mx, off));
    }
    int wid = threadIdx.x >> 6, lane = threadIdx.x & 63;
    if (lane == 0) { smn[wid] = mn; smx[wid] = mx; }
    __syncthreads();
    if (threadIdx.x == 0) {
        float a = smn[0], b = smx[0];
        for (int i = 1; i < 4; ++i) { a = fminf(a, smn[i]); b = fmaxf(b, smx[i]); }
        smn[0] = a; smx[0] = b;
    }
    __syncthreads();
    *omn = smn[0]; *omx = smx[0];
}

// _qround forward: round((x-mn)/scale)*scale + mn, scale = max(mx-mn,1e-8)/63
__device__ void quantize_tensor(const float* __restrict__ src, int n,
                                float* __restrict__ dst, float* smn, float* smx) {
    float mn = 3.4e38f, mx = -3.4e38f;
    for (int i = threadIdx.x; i < n; i += blockDim.x) {
        float v = src[i];
        mn = fminf(mn, v); mx = fmaxf(mx, v);
    }
    float gmn, gmx;
    block_minmax(mn, mx, &gmn, &gmx, smn, smx);
    float scale = fmaxf(gmx - gmn, 1e-8f) / 63.0f;
    for (int i = threadIdx.x; i < n; i += blockDim.x) {
        float v = src[i];
        dst[i] = rintf((v - gmn) / scale) * scale + gmn;
    }
}

// ONE prep launch (42 blocks):
//   0..4   : quantize bias tensors into ws
//   5..15  : grid argmax tables
//   16..39 : weight fragments, layers 1..3 (K-order permuted, see above)
//   40     : weight fragments, layer 0 (4 waves; K rows 5..31 zero; unpermuted)
//   41     : w4 f16-pair pack (x64 scaled, permuted slot order)
__global__ void vinr_prep(
    const float* __restrict__ cb0, const float* __restrict__ ind0,
    const float* __restrict__ cb1, const float* __restrict__ ind1,
    const float* __restrict__ cb2, const float* __restrict__ ind2,
    const float* __restrict__ w0, const float* __restrict__ b0,
    const float* __restrict__ w1, const float* __restrict__ b1,
    const float* __restrict__ w2, const float* __restrict__ b2,
    const float* __restrict__ w3, const float* __restrict__ b3,
    const float* __restrict__ w4, const float* __restrict__ b4,
    float* __restrict__ ws)
{
    __shared__ float smn[4], smx[4];
    if (blockIdx.x < 5) {
        switch (blockIdx.x) {
            case 0: quantize_tensor(b0, 64, ws + BQ0, smn, smx); break;
            case 1: quantize_tensor(b1, 64, ws + BQ1, smn, smx); break;
            case 2: quantize_tensor(b2, 64, ws + BQ2, smn, smx); break;
            case 3: quantize_tensor(b3, 64, ws + BQ3, smn, smx); break;
            case 4: quantize_tensor(b4, 1,  ws + BQ4, smn, smx); break;
        }
    } else if (blockIdx.x < 16) {
        int r = (int)(blockIdx.x - 5) * 256 + (int)threadIdx.x;
        const float* ind = nullptr; const float* cb = nullptr; float* dst = nullptr;
        if (r < 128)       { ind = ind0 + r * 64;          cb = cb0; dst = ws + GT0 + r * 4; }
        else if (r < 640)  { int rr = r - 128;  ind = ind1 + rr * 64; cb = cb1; dst = ws + GT1 + rr * 4; }
        else if (r < 2688) { int rr = r - 640;  ind = ind2 + rr * 64; cb = cb2; dst = ws + GT2 + rr * 4; }
        if (dst) {
            float best = -3.4e38f; int bi = 0;
            for (int j = 0; j < 64; ++j) {
                float v = ind[j];
                if (v > best) { best = v; bi = j; }
            }
            #pragma unroll
            for (int d = 0; d < 4; ++d) dst[d] = cb[bi * 4 + d];
        }
    } else if (blockIdx.x < 40) {
        if (threadIdx.x < 64) {                        // one wave per frag
            int fi = (int)blockIdx.x - 16;             // 0..23
            int lane = (int)threadIdx.x;
            int l = fi >> 3, s = (fi >> 2) & 1, ft = fi & 3;
            const float* w = (l == 0) ? w1 : (l == 1) ? w2 : w3;
            float mn = 3.4e38f, mx = -3.4e38f;
            for (int i = lane; i < 4096; i += 64) {
                float v = w[i];
                mn = fminf(mn, v); mx = fmaxf(mx, v);
            }
            #pragma unroll
            for (int off = 32; off > 0; off >>= 1) {
                mn = fminf(mn, __shfl_xor(mn, off));
                mx = fmaxf(mx, __shfl_xor(mx, off));
            }
            float scale = fmaxf(mx - mn, 1e-8f) / 63.0f;
            int q = lane >> 4, m15 = lane & 15;
            int n = ft * 16 + m15;
            f16x8 hi;
            #pragma unroll
            for (int j = 0; j < 8; ++j) {
                // permuted K-order: slot (s,q,j) carries logical input feature
                // r(t) = 32*s + 16*(j>>2) + 4*q + (j&3)
                int k = s * 32 + (j >> 2) * 16 + q * 4 + (j & 3);
                float v = w[k * 64 + n];
                v = (rintf((v - mn) / scale) * scale + mn) * WSCALE;
                hi[j] = (_Float16)v;
            }
            f16x8* base = (f16x8*)(ws + FRAG_OFF);
            base[fi * 64 + lane] = hi;
        }
    } else if (blockIdx.x == 40) {
        // layer-0 frags: wave wv -> ft wv; W0 is [5][64], K padded to 32 with zeros.
        // Layer-0 B slots are staged by the main kernel in natural order -> no perm.
        int wv = (int)threadIdx.x >> 6;
        int lane = (int)threadIdx.x & 63;
        if (wv < 4) {
            float mn = 3.4e38f, mx = -3.4e38f;
            for (int i = lane; i < 320; i += 64) {
                float v = w0[i];
                mn = fminf(mn, v); mx = fmaxf(mx, v);
            }
            #pragma unroll
            for (int off = 32; off > 0; off >>= 1) {
                mn = fminf(mn, __shfl_xor(mn, off));
                mx = fmaxf(mx, __shfl_xor(mx, off));
            }
            float scale = fmaxf(mx - mn, 1e-8f) / 63.0f;
            int q = lane >> 4, m15 = lane & 15;
            int n = wv * 16 + m15;
            f16x8 hi;
            #pragma unroll
            for (int j = 0; j < 8; ++j) {
                int k = q * 8 + j;
                float v = 0.0f;
                if (k < 5) {
                    float vv = w0[k * 64 + n];
                    v = (rintf((vv - mn) / scale) * scale + mn) * WSCALE;
                }
                hi[j] = (_Float16)v;
            }
            f16x8* base = (f16x8*)(ws + FRAG_OFF);
            base[(24 + wv) * 64 + lane] = hi;
        }
    } else {
        // w4 pack: quantize (self-contained minmax), scale x64, f16 pairs.
        // slot t holds w4[r(t)] so it lines up with the register-resident
        // layer-3 output fragments.
        if (threadIdx.x < 64) {
            int lane = (int)threadIdx.x;
            float v = w4[lane];
            float mn = v, mx = v;
            #pragma unroll
            for (int off = 32; off > 0; off >>= 1) {
                mn = fminf(mn, __shfl_xor(mn, off));
                mx = fmaxf(mx, __shfl_xor(mx, off));
            }
            float scale = fmaxf(mx - mn, 1e-8f) / 63.0f;
            if (lane < 32) {
                int t0 = 2 * lane, t1 = t0 + 1;
                int f0 = ((t0 >> 5) * 32) + (((t0 >> 2) & 1) * 16)
                       + (((t0 >> 3) & 3) * 4) + (t0 & 3);
                int f1 = ((t1 >> 5) * 32) + (((t1 >> 2) & 1) * 16)
                       + (((t1 >> 3) & 3) * 4) + (t1 & 3);
                float q0 = (rintf((w4[f0] - mn) / scale) * scale + mn) * WSCALE;
                float q1 = (rintf((w4[f1] - mn) / scale) * scale + mn) * WSCALE;
                unsigned int* wsU = (unsigned int*)ws;
                wsU[W4P + lane] = pack_f16(q0, q1);
            }
        }
    }
}

// Register-resident activation chain, per-ft pipelined schedule (r2 structure,
// builtins only). gelu trans-diet: 2 trans/pair instead of 4 (NR reciprocal).
__global__ __launch_bounds__(256, 5) void vinr_main(
    const float* __restrict__ x, const float* __restrict__ ws,
    float* __restrict__ out, int N)
{
    __shared__ __align__(16) uint4 ilds[4][32];
    int wave = threadIdx.x >> 6, lane = threadIdx.x & 63;
    int q = lane >> 4, m15 = lane & 15;
    int p = lane & 31, half = lane >> 5;

    int base = (int)blockIdx.x * 128 + wave * 32;
    int idx = base + p;
    int idxc = min(idx, N - 1);
    float2 xr = ((const float2*)x)[idxc];
    float feat  = xr.x;
    float coord = xr.y;

    float g0 = 0.f, g1 = 0.f, g2 = 0.f, g3 = 0.f;
    const int RES[3]  = {128, 512, 2048};
    const int GOFF[3] = {GT0, GT1, GT2};
    #pragma unroll
    for (int gi = 0; gi < 3; ++gi) {
        int res = RES[gi];
        float c = (coord + 1.0f) * 0.5f * (float)(res - 1);
        int left  = min((int)floorf(c), res - 2);
        int right = max((int)ceilf(c), 1);
        float w = c - (float)left;
        const float4* gt = (const float4*)(ws + GOFF[gi]);
        float4 gl = gt[left];
        float4 gr = gt[right];
        float wm = 1.0f - w;
        g0 += wm * gl.x + w * gr.x;
        g1 += wm * gl.y + w * gr.y;
        g2 += wm * gl.z + w * gr.z;
        g3 += wm * gl.w + w * gr.w;
    }

    // stage layer-0 inputs: point p -> slots [g0,g1,g2,g3,feat,0,0,0]
    if (half == 0)
        ilds[wave][p] = make_uint4(pack_f16(g0, g1), pack_f16(g2, g3),
                                   pack_f16(feat, 0.0f), 0u);

    const f16x8* fh = (const f16x8*)(ws + FRAG_OFF);
    f16x8 zfrag = __builtin_bit_cast(f16x8, (uintx4){0u, 0u, 0u, 0u});
    const floatx4 zacc = (floatx4){0.f, 0.f, 0.f, 0.f};
    const floatx2 winv2 = splat2(WINV);

    f16x8 Bc[2][2];       // current B-fragments (s x pt), register-resident
    uintx4 Bn[2][2];      // next-layer B-fragments under construction

    // ---- layer 0 (5 -> 64), per-ft pipeline
    {
        f16x8 B0[2];
        #pragma unroll
        for (int pt = 0; pt < 2; ++pt) {
            B0[pt] = zfrag;
            if (q == 0) {
                uint4 r = ilds[wave][pt * 16 + m15];
                B0[pt] = frag_from(make_uint2(r.x, r.y), make_uint2(r.z, r.w));
            }
        }
        #pragma unroll
        for (int ft = 0; ft < 4; ++ft) {
            f16x8 Wh = fh[(24 + ft) * 64 + lane];
            float4 bq = *(const float4*)(ws + BQ0 + ft * 16 + q * 4);
            #pragma unroll
            for (int pt = 0; pt < 2; ++pt) {
                floatx4 av = mfma16(Wh, B0[pt], zacc);
                floatx2 a01 = __builtin_elementwise_fma(
                    (floatx2){av[0], av[1]}, winv2, (floatx2){bq.x, bq.y});
                floatx2 a23 = __builtin_elementwise_fma(
                    (floatx2){av[2], av[3]}, winv2, (floatx2){bq.z, bq.w});
                floatx2 v01 = gelu2(a01);
                floatx2 v23 = gelu2(a23);
                Bn[ft >> 1][pt][(ft & 1) * 2]     = pkrtz(v01.x, v01.y);
                Bn[ft >> 1][pt][(ft & 1) * 2 + 1] = pkrtz(v23.x, v23.y);
            }
        }
        #pragma unroll
        for (int s = 0; s < 2; ++s)
            #pragma unroll
            for (int pt = 0; pt < 2; ++pt)
                Bc[s][pt] = __builtin_bit_cast(f16x8, Bn[s][pt]);
    }

    // ---- layers 1..3, per-ft pipeline
    const int BOFF[3] = {BQ1, BQ2, BQ3};
    #pragma unroll
    for (int l = 0; l < 3; ++l) {
        #pragma unroll
        for (int ft = 0; ft < 4; ++ft) {
            f16x8 W0 = fh[(l * 8 + ft) * 64 + lane];          // s=0
            f16x8 W1 = fh[(l * 8 + 4 + ft) * 64 + lane];      // s=1
            float4 bq = *(const float4*)(ws + BOFF[l] + ft * 16 + q * 4);
            #pragma unroll
            for (int pt = 0; pt < 2; ++pt) {
                floatx4 av = mfma16(W0, Bc[0][pt], zacc);
                av = mfma16(W1, Bc[1][pt], av);
                floatx2 a01 = __builtin_elementwise_fma(
                    (floatx2){av[0], av[1]}, winv2, (floatx2){bq.x, bq.y});
                floatx2 a23 = __builtin_elementwise_fma(
                    (floatx2){av[2], av[3]}, winv2, (floatx2){bq.z, bq.w});
                floatx2 v01 = gelu2(a01);
                floatx2 v23 = gelu2(a23);
                Bn[ft >> 1][pt][(ft & 1) * 2]     = pkrtz(v01.x, v01.y);
                Bn[ft >> 1][pt][(ft & 1) * 2 + 1] = pkrtz(v23.x, v23.y);
            }
        }
        #pragma unroll
        for (int s = 0; s < 2; ++s)
            #pragma unroll
            for (int pt = 0; pt < 2; ++pt)
                Bc[s][pt] = __builtin_bit_cast(f16x8, Bn[s][pt]);
    }

    // ---- layer 4: per-lane 16-value dot against permuted w4, reduce over q.
    {
        const unsigned int* wsU = (const unsigned int*)ws;
        float ah0 = 0.0f, ah1 = 0.0f;
        #pragma unroll
        for (int s = 0; s < 2; ++s) {
            uint4 wv = *(const uint4*)(wsU + W4P + 16 * s + 4 * q);
            uintx4 b0 = __builtin_bit_cast(uintx4, Bc[s][0]);
            uintx4 b1 = __builtin_bit_cast(uintx4, Bc[s][1]);
            ah0 = fdot2f(h2(b0[0]), h2(wv.x), ah0);
            ah1 = fdot2f(h2(b1[0]), h2(wv.x), ah1);
            ah0 = fdot2f(h2(b0[1]), h2(wv.y), ah0);
            ah1 = fdot2f(h2(b1[1]), h2(wv.y), ah1);
            ah0 = fdot2f(h2(b0[2]), h2(wv.z), ah0);
            ah1 = fdot2f(h2(b1[2]), h2(wv.z), ah1);
            ah0 = fdot2f(h2(b0[3]), h2(wv.w), ah0);
            ah1 = fdot2f(h2(b1[3]), h2(wv.w), ah1);
        }
        ah0 += __shfl_xor(ah0, 16);
        ah0 += __shfl_xor(ah0, 32);
        ah1 += __shfl_xor(ah1, 16);
        ah1 += __shfl_xor(ah1, 32);
        float b4v = ws[BQ4];
        int oidx = base + lane;
        if (lane < 32 && oidx < N) {
            float sel = (lane & 16) ? ah1 : ah0;
            out[oidx] = tanh_fast(fmaf(sel, WINV, b4v));
        }
    }
}

extern "C" void kernel_launch(void* const* d_in, const int* in_sizes, int n_in,
                              void* d_out, int out_size, void* d_ws, size_t ws_size,
                              hipStream_t stream) {
    const float* x    = (const float*)d_in[0];
    const float* cb0  = (const float*)d_in[1];
    const float* ind0 = (const float*)d_in[2];
    const float* cb1  = (const float*)d_in[3];
    const float* ind1 = (const float*)d_in[4];
    const float* cb2  = (const float*)d_in[5];
    const float* ind2 = (const float*)d_in[6];
    const float* w0 = (const float*)d_in[7],  * b0 = (const float*)d_in[8];
    const float* w1 = (const float*)d_in[9],  * b1 = (const float*)d_in[10];
    const float* w2 = (const float*)d_in[11], * b2 = (const float*)d_in[12];
    const float* w3 = (const float*)d_in[13], * b3 = (const float*)d_in[14];
    const float* w4 = (const float*)d_in[15], * b4 = (const float*)d_in[16];
    float* ws  = (float*)d_ws;
    float* out = (float*)d_out;

    int N = in_sizes[0] / 2;  // 1<<20

    vinr_prep<<<42, 256, 0, stream>>>(cb0, ind0, cb1, ind1, cb2, ind2,
                                      w0, b0, w1, b1, w2, b2, w3, b3, w4, b4, ws);
    int blocks = (N + 127) / 128;
    vinr_main<<<blocks, 256, 0, stream>>>(x, ws, out, N);
}

// Round 7
// 215.564 us; speedup vs baseline: 1.0374x; 1.0374x over previous
//
#include <hip/hip_runtime.h>
#include <hip/hip_bf16.h>
#include <math.h>

// ---------------- ws layout (float/u32 offsets) ----------------
#define BQ0 320
#define BQ1 4480
#define BQ2 8640
#define BQ3 12800
#define BQ4 12928
#define GT0 12932
#define GT1 13444
#define GT2 15492
// Packed f16 MFMA weight fragments, x64-scaled, single RNE f16.
// fi 0..23 = layers 1..3 ((l*2+s)*4+ft), fi 24..27 = layer 0 (K rows 5..31 zero).
// K-order of layers 1..3 frags and of W4P is PERMUTED so that the previous
// layer's accumulator registers (after gelu+pkrtz) directly form the next
// layer's B-fragment: B-slot t holds prev physical row
//   r(t) = 32*(t>>5) + 16*((t>>2)&1) + 4*((t>>3)&3) + (t&3).
#define FRAG_OFF 23684
#define W4P 38020
#define WSCALE 64.0f
#define WINV   0.015625f

// HARD RULES (r3-r6 lessons):
//  - NO inline-asm VALU in the dataflow: gfx950 lacks packed f32 min/max
//    (r3); asm consuming MFMA or trans results races — hazard recognizer
//    does not pad INLINEASM consumers (r4/r5).
//  - v_rcp/v_exp are CHEAP on gfx950: NR-reciprocal substitution regressed
//    (r6) — do not trade trans for extra VALU ops.
//  - __launch_bounds__(256,6) is the measured-best config (r2); the 10 MB
//    WRITE_SIZE it induces is benign.

typedef _Float16 f16x8 __attribute__((ext_vector_type(8)));
typedef _Float16 f16x2 __attribute__((ext_vector_type(2)));
typedef float floatx4 __attribute__((ext_vector_type(4)));
typedef float floatx2 __attribute__((ext_vector_type(2)));
typedef unsigned int uintx4 __attribute__((ext_vector_type(4)));

__device__ inline floatx4 mfma16(f16x8 a, f16x8 b, floatx4 c) {
    return __builtin_amdgcn_mfma_f32_16x16x32_f16(a, b, c, 0, 0, 0);
}
__device__ inline floatx2 splat2(float c) { return (floatx2){c, c}; }
__device__ inline floatx4 splat4(float c) { return (floatx4){c, c, c, c}; }

// single-inst packed f32->f16 pair conversion (RTZ); returns __fp16x2.
__device__ inline unsigned int pkrtz(float a, float b) {
    auto r = __builtin_amdgcn_cvt_pkrtz(a, b);
    return __builtin_bit_cast(unsigned int, r);
}
// exact RNE pack (prep-side / layer-0 staging)
__device__ inline unsigned int pack_f16(float a, float b) {
    unsigned short ua = __builtin_bit_cast(unsigned short, (_Float16)a);
    unsigned short ub = __builtin_bit_cast(unsigned short, (_Float16)b);
    return (unsigned int)ua | ((unsigned int)ub << 16);
}
__device__ inline f16x8 frag_from(uint2 a, uint2 b) {
    uintx4 u = {a.x, a.y, b.x, b.y};
    return __builtin_bit_cast(f16x8, u);
}
__device__ inline f16x2 h2(unsigned int u) { return __builtin_bit_cast(f16x2, u); }

#if __has_builtin(__builtin_amdgcn_fdot2)
__device__ inline float fdot2f(f16x2 a, f16x2 b, float c) {
    return __builtin_amdgcn_fdot2(a, b, c, false);
}
#else
__device__ inline float fdot2f(f16x2 a, f16x2 b, float c) {
    return fmaf((float)a[0], (float)b[0], fmaf((float)a[1], (float)b[1], c));
}
#endif

// Packed-quad gelu: 0.5*(x + |x|*erf_mag(|x|/sqrt2)), AS 7.1.25 erf (2.5e-5).
// Same per-element ops/rounding as the r2 gelu2 (bit-identical output) —
// widened to floatx4 so the backend can select VOP3P packed-f32
// (v_pk_fma_f32 / v_pk_mul_f32) from vector IR with hazards handled.
__device__ inline floatx4 gelu4(floatx4 x) {
    floatx4 ax = __builtin_elementwise_abs(x);
    floatx4 z  = ax * splat4(0.70710678118654752f);
    floatx4 den = __builtin_elementwise_fma(z, splat4(0.47047f), splat4(1.0f));
    floatx4 t;
    t[0] = __builtin_amdgcn_rcpf(den[0]);
    t[1] = __builtin_amdgcn_rcpf(den[1]);
    t[2] = __builtin_amdgcn_rcpf(den[2]);
    t[3] = __builtin_amdgcn_rcpf(den[3]);
    floatx4 p = __builtin_elementwise_fma(t, splat4(0.7478556f), splat4(-0.0958798f));
    p = __builtin_elementwise_fma(t, p, splat4(0.3480242f));
    p = p * t;
    floatx4 ea = (z * z) * splat4(-1.44269504088896f);
    floatx4 e;
    e[0] = __builtin_amdgcn_exp2f(ea[0]);
    e[1] = __builtin_amdgcn_exp2f(ea[1]);
    e[2] = __builtin_amdgcn_exp2f(ea[2]);
    e[3] = __builtin_amdgcn_exp2f(ea[3]);
    floatx4 er = __builtin_elementwise_fma(-p, e, splat4(1.0f));
    return __builtin_elementwise_fma(ax, er, x) * splat4(0.5f);
}

__device__ inline float tanh_fast(float x) {
    float e = __builtin_amdgcn_exp2f(x * 2.88539008177793f);
    return fmaf(-2.0f, __builtin_amdgcn_rcpf(e + 1.0f), 1.0f);
}

__device__ void block_minmax(float mn, float mx, float* omn, float* omx,
                             float* smn, float* smx) {
    __syncthreads();
    #pragma unroll
    for (int off = 32; off > 0; off >>= 1) {
        mn = fminf(mn, __shfl_down(mn, off));
        mx = fmaxf(mx, __shfl_down(mx, off));
    }
    int wid = threadIdx.x >> 6, lane = threadIdx.x & 63;
    if (lane == 0) { smn[wid] = mn; smx[wid] = mx; }
    __syncthreads();
    if (threadIdx.x == 0) {
        float a = smn[0], b = smx[0];
        for (int i = 1; i < 4; ++i) { a = fminf(a, smn[i]); b = fmaxf(b, smx[i]); }
        smn[0] = a; smx[0] = b;
    }
    __syncthreads();
    *omn = smn[0]; *omx = smx[0];
}

// _qround forward: round((x-mn)/scale)*scale + mn, scale = max(mx-mn,1e-8)/63
__device__ void quantize_tensor(const float* __restrict__ src, int n,
                                float* __restrict__ dst, float* smn, float* smx) {
    float mn = 3.4e38f, mx = -3.4e38f;
    for (int i = threadIdx.x; i < n; i += blockDim.x) {
        float v = src[i];
        mn = fminf(mn, v); mx = fmaxf(mx, v);
    }
    float gmn, gmx;
    block_minmax(mn, mx, &gmn, &gmx, smn, smx);
    float scale = fmaxf(gmx - gmn, 1e-8f) / 63.0f;
    for (int i = threadIdx.x; i < n; i += blockDim.x) {
        float v = src[i];
        dst[i] = rintf((v - gmn) / scale) * scale + gmn;
    }
}

// ONE prep launch (42 blocks):
//   0..4   : quantize bias tensors into ws
//   5..15  : grid argmax tables
//   16..39 : weight fragments, layers 1..3 (K-order permuted, see above)
//   40     : weight fragments, layer 0 (4 waves; K rows 5..31 zero; unpermuted)
//   41     : w4 f16-pair pack (x64 scaled, permuted slot order)
__global__ void vinr_prep(
    const float* __restrict__ cb0, const float* __restrict__ ind0,
    const float* __restrict__ cb1, const float* __restrict__ ind1,
    const float* __restrict__ cb2, const float* __restrict__ ind2,
    const float* __restrict__ w0, const float* __restrict__ b0,
    const float* __restrict__ w1, const float* __restrict__ b1,
    const float* __restrict__ w2, const float* __restrict__ b2,
    const float* __restrict__ w3, const float* __restrict__ b3,
    const float* __restrict__ w4, const float* __restrict__ b4,
    float* __restrict__ ws)
{
    __shared__ float smn[4], smx[4];
    if (blockIdx.x < 5) {
        switch (blockIdx.x) {
            case 0: quantize_tensor(b0, 64, ws + BQ0, smn, smx); break;
            case 1: quantize_tensor(b1, 64, ws + BQ1, smn, smx); break;
            case 2: quantize_tensor(b2, 64, ws + BQ2, smn, smx); break;
            case 3: quantize_tensor(b3, 64, ws + BQ3, smn, smx); break;
            case 4: quantize_tensor(b4, 1,  ws + BQ4, smn, smx); break;
        }
    } else if (blockIdx.x < 16) {
        int r = (int)(blockIdx.x - 5) * 256 + (int)threadIdx.x;
        const float* ind = nullptr; const float* cb = nullptr; float* dst = nullptr;
        if (r < 128)       { ind = ind0 + r * 64;          cb = cb0; dst = ws + GT0 + r * 4; }
        else if (r < 640)  { int rr = r - 128;  ind = ind1 + rr * 64; cb = cb1; dst = ws + GT1 + rr * 4; }
        else if (r < 2688) { int rr = r - 640;  ind = ind2 + rr * 64; cb = cb2; dst = ws + GT2 + rr * 4; }
        if (dst) {
            float best = -3.4e38f; int bi = 0;
            for (int j = 0; j < 64; ++j) {
                float v = ind[j];
                if (v > best) { best = v; bi = j; }
            }
            #pragma unroll
            for (int d = 0; d < 4; ++d) dst[d] = cb[bi * 4 + d];
        }
    } else if (blockIdx.x < 40) {
        if (threadIdx.x < 64) {                        // one wave per frag
            int fi = (int)blockIdx.x - 16;             // 0..23
            int lane = (int)threadIdx.x;
            int l = fi >> 3, s = (fi >> 2) & 1, ft = fi & 3;
            const float* w = (l == 0) ? w1 : (l == 1) ? w2 : w3;
            float mn = 3.4e38f, mx = -3.4e38f;
            for (int i = lane; i < 4096; i += 64) {
                float v = w[i];
                mn = fminf(mn, v); mx = fmaxf(mx, v);
            }
            #pragma unroll
            for (int off = 32; off > 0; off >>= 1) {
                mn = fminf(mn, __shfl_xor(mn, off));
                mx = fmaxf(mx, __shfl_xor(mx, off));
            }
            float scale = fmaxf(mx - mn, 1e-8f) / 63.0f;
            int q = lane >> 4, m15 = lane & 15;
            int n = ft * 16 + m15;
            f16x8 hi;
            #pragma unroll
            for (int j = 0; j < 8; ++j) {
                // permuted K-order: slot (s,q,j) carries logical input feature
                // r(t) = 32*s + 16*(j>>2) + 4*q + (j&3)
                int k = s * 32 + (j >> 2) * 16 + q * 4 + (j & 3);
                float v = w[k * 64 + n];
                v = (rintf((v - mn) / scale) * scale + mn) * WSCALE;
                hi[j] = (_Float16)v;
            }
            f16x8* base = (f16x8*)(ws + FRAG_OFF);
            base[fi * 64 + lane] = hi;
        }
    } else if (blockIdx.x == 40) {
        // layer-0 frags: wave wv -> ft wv; W0 is [5][64], K padded to 32 with zeros.
        // Layer-0 B slots are staged by the main kernel in natural order -> no perm.
        int wv = (int)threadIdx.x >> 6;
        int lane = (int)threadIdx.x & 63;
        if (wv < 4) {
            float mn = 3.4e38f, mx = -3.4e38f;
            for (int i = lane; i < 320; i += 64) {
                float v = w0[i];
                mn = fminf(mn, v); mx = fmaxf(mx, v);
            }
            #pragma unroll
            for (int off = 32; off > 0; off >>= 1) {
                mn = fminf(mn, __shfl_xor(mn, off));
                mx = fmaxf(mx, __shfl_xor(mx, off));
            }
            float scale = fmaxf(mx - mn, 1e-8f) / 63.0f;
            int q = lane >> 4, m15 = lane & 15;
            int n = wv * 16 + m15;
            f16x8 hi;
            #pragma unroll
            for (int j = 0; j < 8; ++j) {
                int k = q * 8 + j;
                float v = 0.0f;
                if (k < 5) {
                    float vv = w0[k * 64 + n];
                    v = (rintf((vv - mn) / scale) * scale + mn) * WSCALE;
                }
                hi[j] = (_Float16)v;
            }
            f16x8* base = (f16x8*)(ws + FRAG_OFF);
            base[(24 + wv) * 64 + lane] = hi;
        }
    } else {
        // w4 pack: quantize (self-contained minmax), scale x64, f16 pairs.
        // slot t holds w4[r(t)] so it lines up with the register-resident
        // layer-3 output fragments.
        if (threadIdx.x < 64) {
            int lane = (int)threadIdx.x;
            float v = w4[lane];
            float mn = v, mx = v;
            #pragma unroll
            for (int off = 32; off > 0; off >>= 1) {
                mn = fminf(mn, __shfl_xor(mn, off));
                mx = fmaxf(mx, __shfl_xor(mx, off));
            }
            float scale = fmaxf(mx - mn, 1e-8f) / 63.0f;
            if (lane < 32) {
                int t0 = 2 * lane, t1 = t0 + 1;
                int f0 = ((t0 >> 5) * 32) + (((t0 >> 2) & 1) * 16)
                       + (((t0 >> 3) & 3) * 4) + (t0 & 3);
                int f1 = ((t1 >> 5) * 32) + (((t1 >> 2) & 1) * 16)
                       + (((t1 >> 3) & 3) * 4) + (t1 & 3);
                float q0 = (rintf((w4[f0] - mn) / scale) * scale + mn) * WSCALE;
                float q1 = (rintf((w4[f1] - mn) / scale) * scale + mn) * WSCALE;
                unsigned int* wsU = (unsigned int*)ws;
                wsU[W4P + lane] = pack_f16(q0, q1);
            }
        }
    }
}

// Register-resident activation chain, per-ft pipelined schedule (r2 structure,
// builtins only, launch_bounds (256,6) = measured-best). Epilogue widened to
// floatx4 (gelu4) to invite VOP3P packed-f32 selection by the backend.
__global__ __launch_bounds__(256, 6) void vinr_main(
    const float* __restrict__ x, const float* __restrict__ ws,
    float* __restrict__ out, int N)
{
    __shared__ __align__(16) uint4 ilds[4][32];
    int wave = threadIdx.x >> 6, lane = threadIdx.x & 63;
    int q = lane >> 4, m15 = lane & 15;
    int p = lane & 31, half = lane >> 5;

    int base = (int)blockIdx.x * 128 + wave * 32;
    int idx = base + p;
    int idxc = min(idx, N - 1);
    float2 xr = ((const float2*)x)[idxc];
    float feat  = xr.x;
    float coord = xr.y;

    float g0 = 0.f, g1 = 0.f, g2 = 0.f, g3 = 0.f;
    const int RES[3]  = {128, 512, 2048};
    const int GOFF[3] = {GT0, GT1, GT2};
    #pragma unroll
    for (int gi = 0; gi < 3; ++gi) {
        int res = RES[gi];
        float c = (coord + 1.0f) * 0.5f * (float)(res - 1);
        int left  = min((int)floorf(c), res - 2);
        int right = max((int)ceilf(c), 1);
        float w = c - (float)left;
        const float4* gt = (const float4*)(ws + GOFF[gi]);
        float4 gl = gt[left];
        float4 gr = gt[right];
        float wm = 1.0f - w;
        g0 += wm * gl.x + w * gr.x;
        g1 += wm * gl.y + w * gr.y;
        g2 += wm * gl.z + w * gr.z;
        g3 += wm * gl.w + w * gr.w;
    }

    // stage layer-0 inputs: point p -> slots [g0,g1,g2,g3,feat,0,0,0]
    if (half == 0)
        ilds[wave][p] = make_uint4(pack_f16(g0, g1), pack_f16(g2, g3),
                                   pack_f16(feat, 0.0f), 0u);

    const f16x8* fh = (const f16x8*)(ws + FRAG_OFF);
    f16x8 zfrag = __builtin_bit_cast(f16x8, (uintx4){0u, 0u, 0u, 0u});
    const floatx4 zacc = (floatx4){0.f, 0.f, 0.f, 0.f};
    const floatx4 winv4 = splat4(WINV);

    f16x8 Bc[2][2];       // current B-fragments (s x pt), register-resident
    uintx4 Bn[2][2];      // next-layer B-fragments under construction

    // ---- layer 0 (5 -> 64), per-ft pipeline
    {
        f16x8 B0[2];
        #pragma unroll
        for (int pt = 0; pt < 2; ++pt) {
            B0[pt] = zfrag;
            if (q == 0) {
                uint4 r = ilds[wave][pt * 16 + m15];
                B0[pt] = frag_from(make_uint2(r.x, r.y), make_uint2(r.z, r.w));
            }
        }
        #pragma unroll
        for (int ft = 0; ft < 4; ++ft) {
            f16x8 Wh = fh[(24 + ft) * 64 + lane];
            floatx4 bq = *(const floatx4*)(ws + BQ0 + ft * 16 + q * 4);
            #pragma unroll
            for (int pt = 0; pt < 2; ++pt) {
                floatx4 av = mfma16(Wh, B0[pt], zacc);
                floatx4 a = __builtin_elementwise_fma(av, winv4, bq);
                floatx4 v = gelu4(a);
                Bn[ft >> 1][pt][(ft & 1) * 2]     = pkrtz(v[0], v[1]);
                Bn[ft >> 1][pt][(ft & 1) * 2 + 1] = pkrtz(v[2], v[3]);
            }
        }
        #pragma unroll
        for (int s = 0; s < 2; ++s)
            #pragma unroll
            for (int pt = 0; pt < 2; ++pt)
                Bc[s][pt] = __builtin_bit_cast(f16x8, Bn[s][pt]);
    }

    // ---- layers 1..3, per-ft pipeline
    const int BOFF[3] = {BQ1, BQ2, BQ3};
    #pragma unroll
    for (int l = 0; l < 3; ++l) {
        #pragma unroll
        for (int ft = 0; ft < 4; ++ft) {
            f16x8 W0 = fh[(l * 8 + ft) * 64 + lane];          // s=0
            f16x8 W1 = fh[(l * 8 + 4 + ft) * 64 + lane];      // s=1
            floatx4 bq = *(const floatx4*)(ws + BOFF[l] + ft * 16 + q * 4);
            #pragma unroll
            for (int pt = 0; pt < 2; ++pt) {
                floatx4 av = mfma16(W0, Bc[0][pt], zacc);
                av = mfma16(W1, Bc[1][pt], av);
                floatx4 a = __builtin_elementwise_fma(av, winv4, bq);
                floatx4 v = gelu4(a);
                Bn[ft >> 1][pt][(ft & 1) * 2]     = pkrtz(v[0], v[1]);
                Bn[ft >> 1][pt][(ft & 1) * 2 + 1] = pkrtz(v[2], v[3]);
            }
        }
        #pragma unroll
        for (int s = 0; s < 2; ++s)
            #pragma unroll
            for (int pt = 0; pt < 2; ++pt)
                Bc[s][pt] = __builtin_bit_cast(f16x8, Bn[s][pt]);
    }

    // ---- layer 4: per-lane 16-value dot against permuted w4, reduce over q.
    {
        const unsigned int* wsU = (const unsigned int*)ws;
        float ah0 = 0.0f, ah1 = 0.0f;
        #pragma unroll
        for (int s = 0; s < 2; ++s) {
            uint4 wv = *(const uint4*)(wsU + W4P + 16 * s + 4 * q);
            uintx4 b0 = __builtin_bit_cast(uintx4, Bc[s][0]);
            uintx4 b1 = __builtin_bit_cast(uintx4, Bc[s][1]);
            ah0 = fdot2f(h2(b0[0]), h2(wv.x), ah0);
            ah1 = fdot2f(h2(b1[0]), h2(wv.x), ah1);
            ah0 = fdot2f(h2(b0[1]), h2(wv.y), ah0);
            ah1 = fdot2f(h2(b1[1]), h2(wv.y), ah1);
            ah0 = fdot2f(h2(b0[2]), h2(wv.z), ah0);
            ah1 = fdot2f(h2(b1[2]), h2(wv.z), ah1);
            ah0 = fdot2f(h2(b0[3]), h2(wv.w), ah0);
            ah1 = fdot2f(h2(b1[3]), h2(wv.w), ah1);
        }
        ah0 += __shfl_xor(ah0, 16);
        ah0 += __shfl_xor(ah0, 32);
        ah1 += __shfl_xor(ah1, 16);
        ah1 += __shfl_xor(ah1, 32);
        float b4v = ws[BQ4];
        int oidx = base + lane;
        if (lane < 32 && oidx < N) {
            float sel = (lane & 16) ? ah1 : ah0;
            out[oidx] = tanh_fast(fmaf(sel, WINV, b4v));
        }
    }
}

extern "C" void kernel_launch(void* const* d_in, const int* in_sizes, int n_in,
                              void* d_out, int out_size, void* d_ws, size_t ws_size,
                              hipStream_t stream) {
    const float* x    = (const float*)d_in[0];
    const float* cb0  = (const float*)d_in[1];
    const float* ind0 = (const float*)d_in[2];
    const float* cb1  = (const float*)d_in[3];
    const float* ind1 = (const float*)d_in[4];
    const float* cb2  = (const float*)d_in[5];
    const float* ind2 = (const float*)d_in[6];
    const float* w0 = (const float*)d_in[7],  * b0 = (const float*)d_in[8];
    const float* w1 = (const float*)d_in[9],  * b1 = (const float*)d_in[10];
    const float* w2 = (const float*)d_in[11], * b2 = (const float*)d_in[12];
    const float* w3 = (const float*)d_in[13], * b3 = (const float*)d_in[14];
    const float* w4 = (const float*)d_in[15], * b4 = (const float*)d_in[16];
    float* ws  = (float*)d_ws;
    float* out = (float*)d_out;

    int N = in_sizes[0] / 2;  // 1<<20

    vinr_prep<<<42, 256, 0, stream>>>(cb0, ind0, cb1, ind1, cb2, ind2,
                                      w0, b0, w1, b1, w2, b2, w3, b3, w4, b4, ws);
    int blocks = (N + 127) / 128;
    vinr_main<<<blocks, 256, 0, stream>>>(x, ws, out, N);
}

// Round 8
// 207.994 us; speedup vs baseline: 1.0752x; 1.0364x over previous
//
#include <hip/hip_runtime.h>
#include <hip/hip_bf16.h>
#include <math.h>

// ---------------- ws layout (float/u32 offsets) ----------------
#define BQ0 320
#define BQ1 4480
#define BQ2 8640
#define BQ3 12800
#define BQ4 12928
#define GT0 12932
#define GT1 13444
#define GT2 15492
// Packed f16 MFMA weight fragments, UNSCALED single RNE f16 (r8: the old x64
// scale was a pow2 no-op for f16 precision; dropping it lets the quantized
// bias ride in the MFMA C-operand so the accumulator IS the pre-activation).
// fi 0..23 = layers 1..3 ((l*2+s)*4+ft), fi 24..27 = layer 0 (K rows 5..31 zero).
// K-order of layers 1..3 frags and of W4P is PERMUTED so that the previous
// layer's accumulator registers (after gelu+pkrtz) directly form the next
// layer's B-fragment: B-slot t holds prev physical row
//   r(t) = 32*(t>>5) + 16*((t>>2)&1) + 4*((t>>3)&3) + (t&3).
#define FRAG_OFF 23684
#define W4P 38020

// HARD RULES (r3-r7 lessons):
//  - NO inline-asm VALU in the dataflow: gfx950 lacks packed f32 min/max
//    (r3); asm consuming MFMA or trans results races — hazard recognizer
//    does not pad INLINEASM consumers (r4/r5).
//  - v_rcp/v_exp are quarter-rate but CHEAP relative to substitutes: NR
//    reciprocal regressed (r6) — never trade 1 trans for >3 VALU ops.
//  - Backend does NOT form v_pk_*_f32 from vector IR either (r7 neutral-to
//    -worse) — issue-count reduction is the only remaining lever.
//  - __launch_bounds__(256,6) is measured-best (r2); its 10 MB WRITE_SIZE
//    scratch artifact is benign.

typedef _Float16 f16x8 __attribute__((ext_vector_type(8)));
typedef _Float16 f16x2 __attribute__((ext_vector_type(2)));
typedef float floatx4 __attribute__((ext_vector_type(4)));
typedef float floatx2 __attribute__((ext_vector_type(2)));
typedef unsigned int uintx4 __attribute__((ext_vector_type(4)));

__device__ inline floatx4 mfma16(f16x8 a, f16x8 b, floatx4 c) {
    return __builtin_amdgcn_mfma_f32_16x16x32_f16(a, b, c, 0, 0, 0);
}
__device__ inline floatx2 splat2(float c) { return (floatx2){c, c}; }

// single-inst packed f32->f16 pair conversion (RTZ); returns __fp16x2.
__device__ inline unsigned int pkrtz(float a, float b) {
    auto r = __builtin_amdgcn_cvt_pkrtz(a, b);
    return __builtin_bit_cast(unsigned int, r);
}
// exact RNE pack (prep-side / layer-0 staging)
__device__ inline unsigned int pack_f16(float a, float b) {
    unsigned short ua = __builtin_bit_cast(unsigned short, (_Float16)a);
    unsigned short ub = __builtin_bit_cast(unsigned short, (_Float16)b);
    return (unsigned int)ua | ((unsigned int)ub << 16);
}
__device__ inline f16x8 frag_from(uint2 a, uint2 b) {
    uintx4 u = {a.x, a.y, b.x, b.y};
    return __builtin_bit_cast(f16x8, u);
}
__device__ inline f16x2 h2(unsigned int u) { return __builtin_bit_cast(f16x2, u); }

#if __has_builtin(__builtin_amdgcn_fdot2)
__device__ inline float fdot2f(f16x2 a, f16x2 b, float c) {
    return __builtin_amdgcn_fdot2(a, b, c, false);
}
#else
__device__ inline float fdot2f(f16x2 a, f16x2 b, float c) {
    return fmaf((float)a[0], (float)b[0], fmaf((float)a[1], (float)b[1], c));
}
#endif

// Lean A&S 7.1.25 gelu (same approximation, restructured):
//   gelu(x) = max(x,0) - |x| * P'(t) * exp2(-0.72134752*x^2)
//   t = 1/(1 + (0.47047/sqrt2)*|x|),  P'(t) = 0.5*(a1 t + a2 t^2 + a3 t^3)
// 10 full-rate + 2 quarter-rate trans per element (was 13 + 2):
// z eliminated (constants pre-folded), 0.5 folded into the polynomial,
// 0.5*(x+|x|) == max(x,0) exactly.
__device__ inline floatx2 gelu2(floatx2 x) {
    floatx2 ax = __builtin_elementwise_abs(x);
    floatx2 den = __builtin_elementwise_fma(ax, splat2(0.33267272f), splat2(1.0f));
    floatx2 t;
    t.x = __builtin_amdgcn_rcpf(den.x);
    t.y = __builtin_amdgcn_rcpf(den.y);
    floatx2 p = __builtin_elementwise_fma(t, splat2(0.3739278f), splat2(-0.0479399f));
    p = __builtin_elementwise_fma(t, p, splat2(0.1740121f));
    p = p * t;                       // P'(t)
    floatx2 g = p * ax;
    floatx2 ea = (ax * ax) * splat2(-0.72134752f);   // -0.5*log2(e)*x^2
    floatx2 e;
    e.x = __builtin_amdgcn_exp2f(ea.x);
    e.y = __builtin_amdgcn_exp2f(ea.y);
    floatx2 m = __builtin_elementwise_max(x, splat2(0.0f));
    return __builtin_elementwise_fma(-g, e, m);
}

__device__ inline float tanh_fast(float x) {
    float e = __builtin_amdgcn_exp2f(x * 2.88539008177793f);
    return fmaf(-2.0f, __builtin_amdgcn_rcpf(e + 1.0f), 1.0f);
}

__device__ void block_minmax(float mn, float mx, float* omn, float* omx,
                             float* smn, float* smx) {
    __syncthreads();
    #pragma unroll
    for (int off = 32; off > 0; off >>= 1) {
        mn = fminf(mn, __shfl_down(mn, off));
        mx = fmaxf(mx, __shfl_down(mx, off));
    }
    int wid = threadIdx.x >> 6, lane = threadIdx.x & 63;
    if (lane == 0) { smn[wid] = mn; smx[wid] = mx; }
    __syncthreads();
    if (threadIdx.x == 0) {
        float a = smn[0], b = smx[0];
        for (int i = 1; i < 4; ++i) { a = fminf(a, smn[i]); b = fmaxf(b, smx[i]); }
        smn[0] = a; smx[0] = b;
    }
    __syncthreads();
    *omn = smn[0]; *omx = smx[0];
}

// _qround forward: round((x-mn)/scale)*scale + mn, scale = max(mx-mn,1e-8)/63
__device__ void quantize_tensor(const float* __restrict__ src, int n,
                                float* __restrict__ dst, float* smn, float* smx) {
    float mn = 3.4e38f, mx = -3.4e38f;
    for (int i = threadIdx.x; i < n; i += blockDim.x) {
        float v = src[i];
        mn = fminf(mn, v); mx = fmaxf(mx, v);
    }
    float gmn, gmx;
    block_minmax(mn, mx, &gmn, &gmx, smn, smx);
    float scale = fmaxf(gmx - gmn, 1e-8f) / 63.0f;
    for (int i = threadIdx.x; i < n; i += blockDim.x) {
        float v = src[i];
        dst[i] = rintf((v - gmn) / scale) * scale + gmn;
    }
}

// ONE prep launch (42 blocks):
//   0..4   : quantize bias tensors into ws
//   5..15  : grid argmax tables
//   16..39 : weight fragments, layers 1..3 (K-order permuted, unscaled)
//   40     : weight fragments, layer 0 (4 waves; K rows 5..31 zero)
//   41     : w4 f16-pair pack (unscaled, permuted slot order)
__global__ void vinr_prep(
    const float* __restrict__ cb0, const float* __restrict__ ind0,
    const float* __restrict__ cb1, const float* __restrict__ ind1,
    const float* __restrict__ cb2, const float* __restrict__ ind2,
    const float* __restrict__ w0, const float* __restrict__ b0,
    const float* __restrict__ w1, const float* __restrict__ b1,
    const float* __restrict__ w2, const float* __restrict__ b2,
    const float* __restrict__ w3, const float* __restrict__ b3,
    const float* __restrict__ w4, const float* __restrict__ b4,
    float* __restrict__ ws)
{
    __shared__ float smn[4], smx[4];
    if (blockIdx.x < 5) {
        switch (blockIdx.x) {
            case 0: quantize_tensor(b0, 64, ws + BQ0, smn, smx); break;
            case 1: quantize_tensor(b1, 64, ws + BQ1, smn, smx); break;
            case 2: quantize_tensor(b2, 64, ws + BQ2, smn, smx); break;
            case 3: quantize_tensor(b3, 64, ws + BQ3, smn, smx); break;
            case 4: quantize_tensor(b4, 1,  ws + BQ4, smn, smx); break;
        }
    } else if (blockIdx.x < 16) {
        int r = (int)(blockIdx.x - 5) * 256 + (int)threadIdx.x;
        const float* ind = nullptr; const float* cb = nullptr; float* dst = nullptr;
        if (r < 128)       { ind = ind0 + r * 64;          cb = cb0; dst = ws + GT0 + r * 4; }
        else if (r < 640)  { int rr = r - 128;  ind = ind1 + rr * 64; cb = cb1; dst = ws + GT1 + rr * 4; }
        else if (r < 2688) { int rr = r - 640;  ind = ind2 + rr * 64; cb = cb2; dst = ws + GT2 + rr * 4; }
        if (dst) {
            float best = -3.4e38f; int bi = 0;
            for (int j = 0; j < 64; ++j) {
                float v = ind[j];
                if (v > best) { best = v; bi = j; }
            }
            #pragma unroll
            for (int d = 0; d < 4; ++d) dst[d] = cb[bi * 4 + d];
        }
    } else if (blockIdx.x < 40) {
        if (threadIdx.x < 64) {                        // one wave per frag
            int fi = (int)blockIdx.x - 16;             // 0..23
            int lane = (int)threadIdx.x;
            int l = fi >> 3, s = (fi >> 2) & 1, ft = fi & 3;
            const float* w = (l == 0) ? w1 : (l == 1) ? w2 : w3;
            float mn = 3.4e38f, mx = -3.4e38f;
            for (int i = lane; i < 4096; i += 64) {
                float v = w[i];
                mn = fminf(mn, v); mx = fmaxf(mx, v);
            }
            #pragma unroll
            for (int off = 32; off > 0; off >>= 1) {
                mn = fminf(mn, __shfl_xor(mn, off));
                mx = fmaxf(mx, __shfl_xor(mx, off));
            }
            float scale = fmaxf(mx - mn, 1e-8f) / 63.0f;
            int q = lane >> 4, m15 = lane & 15;
            int n = ft * 16 + m15;
            f16x8 hi;
            #pragma unroll
            for (int j = 0; j < 8; ++j) {
                // permuted K-order: slot (s,q,j) carries logical input feature
                // r(t) = 32*s + 16*(j>>2) + 4*q + (j&3)
                int k = s * 32 + (j >> 2) * 16 + q * 4 + (j & 3);
                float v = w[k * 64 + n];
                v = rintf((v - mn) / scale) * scale + mn;   // unscaled f16
                hi[j] = (_Float16)v;
            }
            f16x8* base = (f16x8*)(ws + FRAG_OFF);
            base[fi * 64 + lane] = hi;
        }
    } else if (blockIdx.x == 40) {
        // layer-0 frags: wave wv -> ft wv; W0 is [5][64], K padded to 32 with zeros.
        // Layer-0 B slots are staged by the main kernel in natural order -> no perm.
        int wv = (int)threadIdx.x >> 6;
        int lane = (int)threadIdx.x & 63;
        if (wv < 4) {
            float mn = 3.4e38f, mx = -3.4e38f;
            for (int i = lane; i < 320; i += 64) {
                float v = w0[i];
                mn = fminf(mn, v); mx = fmaxf(mx, v);
            }
            #pragma unroll
            for (int off = 32; off > 0; off >>= 1) {
                mn = fminf(mn, __shfl_xor(mn, off));
                mx = fmaxf(mx, __shfl_xor(mx, off));
            }
            float scale = fmaxf(mx - mn, 1e-8f) / 63.0f;
            int q = lane >> 4, m15 = lane & 15;
            int n = wv * 16 + m15;
            f16x8 hi;
            #pragma unroll
            for (int j = 0; j < 8; ++j) {
                int k = q * 8 + j;
                float v = 0.0f;
                if (k < 5) {
                    float vv = w0[k * 64 + n];
                    v = rintf((vv - mn) / scale) * scale + mn;
                }
                hi[j] = (_Float16)v;
            }
            f16x8* base = (f16x8*)(ws + FRAG_OFF);
            base[(24 + wv) * 64 + lane] = hi;
        }
    } else {
        // w4 pack: quantize (self-contained minmax), unscaled f16 pairs.
        // slot t holds w4[r(t)] so it lines up with the register-resident
        // layer-3 output fragments.
        if (threadIdx.x < 64) {
            int lane = (int)threadIdx.x;
            float v = w4[lane];
            float mn = v, mx = v;
            #pragma unroll
            for (int off = 32; off > 0; off >>= 1) {
                mn = fminf(mn, __shfl_xor(mn, off));
                mx = fmaxf(mx, __shfl_xor(mx, off));
            }
            float scale = fmaxf(mx - mn, 1e-8f) / 63.0f;
            if (lane < 32) {
                int t0 = 2 * lane, t1 = t0 + 1;
                int f0 = ((t0 >> 5) * 32) + (((t0 >> 2) & 1) * 16)
                       + (((t0 >> 3) & 3) * 4) + (t0 & 3);
                int f1 = ((t1 >> 5) * 32) + (((t1 >> 2) & 1) * 16)
                       + (((t1 >> 3) & 3) * 4) + (t1 & 3);
                float q0 = rintf((w4[f0] - mn) / scale) * scale + mn;
                float q1 = rintf((w4[f1] - mn) / scale) * scale + mn;
                unsigned int* wsU = (unsigned int*)ws;
                wsU[W4P + lane] = pack_f16(q0, q1);
            }
        }
    }
}

// Register-resident activation chain, per-ft pipelined schedule (r2 structure,
// builtins only, launch_bounds (256,6) = measured-best). r8 diet: quantized
// bias rides in the MFMA C-operand (accumulator = pre-activation directly,
// no scale/bias fma) + lean 10-op gelu.
__global__ __launch_bounds__(256, 6) void vinr_main(
    const float* __restrict__ x, const float* __restrict__ ws,
    float* __restrict__ out, int N)
{
    __shared__ __align__(16) uint4 ilds[4][32];
    int wave = threadIdx.x >> 6, lane = threadIdx.x & 63;
    int q = lane >> 4, m15 = lane & 15;
    int p = lane & 31, half = lane >> 5;

    int base = (int)blockIdx.x * 128 + wave * 32;
    int idx = base + p;
    int idxc = min(idx, N - 1);
    float2 xr = ((const float2*)x)[idxc];
    float feat  = xr.x;
    float coord = xr.y;

    float g0 = 0.f, g1 = 0.f, g2 = 0.f, g3 = 0.f;
    const int RES[3]  = {128, 512, 2048};
    const int GOFF[3] = {GT0, GT1, GT2};
    #pragma unroll
    for (int gi = 0; gi < 3; ++gi) {
        int res = RES[gi];
        float c = (coord + 1.0f) * 0.5f * (float)(res - 1);
        int left  = min((int)floorf(c), res - 2);
        int right = max((int)ceilf(c), 1);
        float w = c - (float)left;
        const float4* gt = (const float4*)(ws + GOFF[gi]);
        float4 gl = gt[left];
        float4 gr = gt[right];
        float wm = 1.0f - w;
        g0 += wm * gl.x + w * gr.x;
        g1 += wm * gl.y + w * gr.y;
        g2 += wm * gl.z + w * gr.z;
        g3 += wm * gl.w + w * gr.w;
    }

    // stage layer-0 inputs: point p -> slots [g0,g1,g2,g3,feat,0,0,0]
    if (half == 0)
        ilds[wave][p] = make_uint4(pack_f16(g0, g1), pack_f16(g2, g3),
                                   pack_f16(feat, 0.0f), 0u);

    const f16x8* fh = (const f16x8*)(ws + FRAG_OFF);
    f16x8 zfrag = __builtin_bit_cast(f16x8, (uintx4){0u, 0u, 0u, 0u});

    f16x8 Bc[2][2];       // current B-fragments (s x pt), register-resident
    uintx4 Bn[2][2];      // next-layer B-fragments under construction

    // ---- layer 0 (5 -> 64), per-ft pipeline
    {
        f16x8 B0[2];
        #pragma unroll
        for (int pt = 0; pt < 2; ++pt) {
            B0[pt] = zfrag;
            if (q == 0) {
                uint4 r = ilds[wave][pt * 16 + m15];
                B0[pt] = frag_from(make_uint2(r.x, r.y), make_uint2(r.z, r.w));
            }
        }
        #pragma unroll
        for (int ft = 0; ft < 4; ++ft) {
            f16x8 Wh = fh[(24 + ft) * 64 + lane];
            floatx4 bq = *(const floatx4*)(ws + BQ0 + ft * 16 + q * 4);
            #pragma unroll
            for (int pt = 0; pt < 2; ++pt) {
                floatx4 av = mfma16(Wh, B0[pt], bq);   // C-init = quantized bias
                floatx2 v01 = gelu2((floatx2){av[0], av[1]});
                floatx2 v23 = gelu2((floatx2){av[2], av[3]});
                Bn[ft >> 1][pt][(ft & 1) * 2]     = pkrtz(v01.x, v01.y);
                Bn[ft >> 1][pt][(ft & 1) * 2 + 1] = pkrtz(v23.x, v23.y);
            }
        }
        #pragma unroll
        for (int s = 0; s < 2; ++s)
            #pragma unroll
            for (int pt = 0; pt < 2; ++pt)
                Bc[s][pt] = __builtin_bit_cast(f16x8, Bn[s][pt]);
    }

    // ---- layers 1..3, per-ft pipeline
    const int BOFF[3] = {BQ1, BQ2, BQ3};
    #pragma unroll
    for (int l = 0; l < 3; ++l) {
        #pragma unroll
        for (int ft = 0; ft < 4; ++ft) {
            f16x8 W0 = fh[(l * 8 + ft) * 64 + lane];          // s=0
            f16x8 W1 = fh[(l * 8 + 4 + ft) * 64 + lane];      // s=1
            floatx4 bq = *(const floatx4*)(ws + BOFF[l] + ft * 16 + q * 4);
            #pragma unroll
            for (int pt = 0; pt < 2; ++pt) {
                floatx4 av = mfma16(W0, Bc[0][pt], bq);   // C-init = bias
                av = mfma16(W1, Bc[1][pt], av);
                floatx2 v01 = gelu2((floatx2){av[0], av[1]});
                floatx2 v23 = gelu2((floatx2){av[2], av[3]});
                Bn[ft >> 1][pt][(ft & 1) * 2]     = pkrtz(v01.x, v01.y);
                Bn[ft >> 1][pt][(ft & 1) * 2 + 1] = pkrtz(v23.x, v23.y);
            }
        }
        #pragma unroll
        for (int s = 0; s < 2; ++s)
            #pragma unroll
            for (int pt = 0; pt < 2; ++pt)
                Bc[s][pt] = __builtin_bit_cast(f16x8, Bn[s][pt]);
    }

    // ---- layer 4: per-lane 16-value dot against permuted w4, reduce over q.
    {
        const unsigned int* wsU = (const unsigned int*)ws;
        float ah0 = 0.0f, ah1 = 0.0f;
        #pragma unroll
        for (int s = 0; s < 2; ++s) {
            uint4 wv = *(const uint4*)(wsU + W4P + 16 * s + 4 * q);
            uintx4 b0 = __builtin_bit_cast(uintx4, Bc[s][0]);
            uintx4 b1 = __builtin_bit_cast(uintx4, Bc[s][1]);
            ah0 = fdot2f(h2(b0[0]), h2(wv.x), ah0);
            ah1 = fdot2f(h2(b1[0]), h2(wv.x), ah1);
            ah0 = fdot2f(h2(b0[1]), h2(wv.y), ah0);
            ah1 = fdot2f(h2(b1[1]), h2(wv.y), ah1);
            ah0 = fdot2f(h2(b0[2]), h2(wv.z), ah0);
            ah1 = fdot2f(h2(b1[2]), h2(wv.z), ah1);
            ah0 = fdot2f(h2(b0[3]), h2(wv.w), ah0);
            ah1 = fdot2f(h2(b1[3]), h2(wv.w), ah1);
        }
        ah0 += __shfl_xor(ah0, 16);
        ah0 += __shfl_xor(ah0, 32);
        ah1 += __shfl_xor(ah1, 16);
        ah1 += __shfl_xor(ah1, 32);
        float b4v = ws[BQ4];
        int oidx = base + lane;
        if (lane < 32 && oidx < N) {
            float sel = (lane & 16) ? ah1 : ah0;
            out[oidx] = tanh_fast(sel + b4v);
        }
    }
}

extern "C" void kernel_launch(void* const* d_in, const int* in_sizes, int n_in,
                              void* d_out, int out_size, void* d_ws, size_t ws_size,
                              hipStream_t stream) {
    const float* x    = (const float*)d_in[0];
    const float* cb0  = (const float*)d_in[1];
    const float* ind0 = (const float*)d_in[2];
    const float* cb1  = (const float*)d_in[3];
    const float* ind1 = (const float*)d_in[4];
    const float* cb2  = (const float*)d_in[5];
    const float* ind2 = (const float*)d_in[6];
    const float* w0 = (const float*)d_in[7],  * b0 = (const float*)d_in[8];
    const float* w1 = (const float*)d_in[9],  * b1 = (const float*)d_in[10];
    const float* w2 = (const float*)d_in[11], * b2 = (const float*)d_in[12];
    const float* w3 = (const float*)d_in[13], * b3 = (const float*)d_in[14];
    const float* w4 = (const float*)d_in[15], * b4 = (const float*)d_in[16];
    float* ws  = (float*)d_ws;
    float* out = (float*)d_out;

    int N = in_sizes[0] / 2;  // 1<<20

    vinr_prep<<<42, 256, 0, stream>>>(cb0, ind0, cb1, ind1, cb2, ind2,
                                      w0, b0, w1, b1, w2, b2, w3, b3, w4, b4, ws);
    int blocks = (N + 127) / 128;
    vinr_main<<<blocks, 256, 0, stream>>>(x, ws, out, N);
}